// Round 1
// baseline (183.285 us; speedup 1.0000x reference)
//
#include <hip/hip_runtime.h>
#include <hip/hip_bf16.h>

// Problem constants
#define BS   4
#define C    256
#define HW   4096          // 64*64
#define NPIX 16384         // 4*4096
#define NCH  289           // cost-volume channels (17*17)
#define MO   17
#define PH   80            // padded 64+2*8
#define PW   80
#define C1   144
#define C2   49
#define ASTR 264           // cv LDS row stride in bf16 elems
#define ICP  320           // agg1 padded input channels (289 -> 320)
#define IC3  192           // agg2 padded input channels (144 -> 192 = 3*64)
#define CVP  70            // cv padded spatial (64 + 2*3)
#define CVC  320           // cv padded channels
#define CH64 72            // 64-ch chunk LDS stride (64+8): bank-balanced

typedef __bf16  bf16x8 __attribute__((ext_vector_type(8)));
typedef float   f32x4  __attribute__((ext_vector_type(4)));
typedef unsigned short us8 __attribute__((ext_vector_type(8)));

// ---------------------------------------------------------------------------
// Setup kernel: prep (halo zeros + weight rearranges) + f1 norm-transpose +
// f2 pad-transpose, dispatched by blockIdx range. 9150 blocks total.
// f1 tile shrunk 32px -> 16px so shmem = 16.5 KB -> 8 blocks/CU (was 4).
__device__ __forceinline__ void halo_zero_dev(unsigned short* p, int H, int halo,
                                              int Cc, int blk, int t) {
    int W = H;
    int inter = H - 2 * halo;
    int total_pos = H * W - inter * inter;
    int chunks = Cc >> 3;
    size_t tot = (size_t)total_pos * chunks * BS;
    size_t idx = (size_t)blk * 256 + t;
    if (idx >= tot) return;
    int c8 = (int)(idx % chunks);
    size_t r = idx / chunks;
    int pos = (int)(r % total_pos);
    int b = (int)(r / total_pos);
    int h, w;
    int topbot = 2 * halo * W;
    if (pos < halo * W) { h = pos / W; w = pos % W; }
    else if (pos < topbot) { int q = pos - halo * W; h = H - halo + q / W; w = q % W; }
    else {
        int q = pos - topbot;
        int row = q / (2 * halo), off = q % (2 * halo);
        h = halo + row;
        w = (off < halo) ? off : (W - 2 * halo + off);
    }
    us8 z = {0, 0, 0, 0, 0, 0, 0, 0};
    *(us8*)&p[(((size_t)b * H + h) * W + w) * Cc + c8 * 8] = z;
}

__global__ void setup_kernel(unsigned short* __restrict__ x2bf, unsigned short* __restrict__ cvp,
                             unsigned short* __restrict__ avp, unsigned short* __restrict__ h1p,
                             const float* __restrict__ w1, unsigned short* __restrict__ wb1,
                             const float* __restrict__ w2, unsigned short* __restrict__ wb2,
                             const float* __restrict__ att_w, float* __restrict__ wdwp,
                             const float* __restrict__ f1, unsigned short* __restrict__ x1bf,
                             const float* __restrict__ f2) {
    __shared__ float shmem[16 * 257 + 16];
    int blk = blockIdx.x;
    int t = threadIdx.x;
    if (blk < 4030) {
        if (blk < 1152) { halo_zero_dev(x2bf, PH, 8, C, blk, t); return; }
        if (blk < 1655) { halo_zero_dev(cvp, CVP, 3, CVC, blk - 1152, t); return; }
        if (blk < 1818) { halo_zero_dev(avp, 66, 1, ICP, blk - 1655, t); return; }
        if (blk < 1916) { halo_zero_dev(h1p, 66, 1, IC3, blk - 1818, t); return; }
        if (blk < 3536) {                 // w1 -> [9][144][320]
            int idx = (blk - 1916) * 256 + t;
            int tap = idx / (C1 * ICP);
            int r = idx - tap * (C1 * ICP);
            int oc = r / ICP;
            int ic = r - oc * ICP;
            float v = (ic < NCH) ? w1[((size_t)(oc * NCH + ic)) * 9 + tap] : 0.f;
            __hip_bfloat16 hb = __float2bfloat16(v);
            wb1[idx] = *(unsigned short*)&hb;
            return;
        }
        if (blk < 3968) {                 // w2 -> [9][64][192]
            int idx = (blk - 3536) * 256 + t;
            int tap = idx / (64 * IC3);
            int r = idx - tap * (64 * IC3);
            int oc = r / IC3;
            int ic = r - oc * IC3;
            float v = (oc < C2 && ic < C1) ? w2[((size_t)(oc * C1 + ic)) * 9 + tap] : 0.f;
            __hip_bfloat16 hb = __float2bfloat16(v);
            wb2[idx] = *(unsigned short*)&hb;
            return;
        }
        {                                 // dw -> [49][320]
            int idx = (blk - 3968) * 256 + t;
            if (idx >= 49 * CVC) return;
            int tap = idx / CVC;
            int ch = idx - tap * CVC;
            wdwp[idx] = (ch < NCH) ? att_w[ch * 49 + tap] : 0.f;
        }
        return;
    }
    if (blk < 5054) {
        // f1: fused norm + transpose, 16-px tiles (1024 blocks)
        float* tileT = shmem;             // [16][257]
        float* invS = shmem + 16 * 257;
        int bb = blk - 4030;
        int pblk = bb & 255, b = bb >> 8;
        int p0 = pblk * 16;
        int tx = t & 15, ty = t >> 4;     // 16 x 16 threads
        const float* s = f1 + (size_t)b * C * HW;
#pragma unroll
        for (int i2 = 0; i2 < 16; ++i2) {
            int c = ty + 16 * i2;
            tileT[tx * 257 + c] = s[(size_t)c * HW + p0 + tx];
        }
        __syncthreads();
        int px = t >> 4;                  // pixel 0..15
        int l = t & 15;                   // 16 lanes per pixel (contiguous)
        float ssum = 0.f;
#pragma unroll
        for (int j2 = 0; j2 < 16; ++j2) {
            float v = tileT[px * 257 + l + 16 * j2];
            ssum += v * v;
        }
        ssum += __shfl_xor(ssum, 1);
        ssum += __shfl_xor(ssum, 2);
        ssum += __shfl_xor(ssum, 4);
        ssum += __shfl_xor(ssum, 8);
        if (l == 0) invS[px] = 1.0f / fmaxf(sqrtf(ssum), 1e-12f);
        __syncthreads();
#pragma unroll 4
        for (int p = 0; p < 16; ++p) {
            float v = tileT[p * 257 + t] * invS[p];
            __hip_bfloat16 hb = __float2bfloat16(v);
            x1bf[((size_t)b * HW + p0 + p) * C + t] = *(unsigned short*)&hb;
        }
        return;
    }
    {
        // f2: pad transpose
        float* tile = shmem;              // [32][33]
        int bb = blk - 5054;
        int pblk = bb & 127;
        int cblk = (bb >> 7) & 7;
        int b    = bb >> 10;
        int tx = t & 31, ty = t >> 5;
        int c0 = cblk * 32, p0 = pblk * 32;
        const float* s = f2 + (size_t)b * C * HW;
#pragma unroll
        for (int i = 0; i < 4; ++i) {
            int c = c0 + ty + 8 * i;
            tile[(ty + 8 * i) * 33 + tx] = s[(size_t)c * HW + p0 + tx];
        }
        __syncthreads();
#pragma unroll
        for (int i = 0; i < 4; ++i) {
            int p = p0 + ty + 8 * i;
            float v = tile[tx * 33 + ty + 8 * i];
            int c = c0 + tx;
            int h = p >> 6, w = p & 63;
            __hip_bfloat16 hb = __float2bfloat16(v);
            x2bf[(((size_t)b * PH + h + 8) * PW + (w + 8)) * C + c] = *(unsigned short*)&hb;
        }
    }
}

// ---------------------------------------------------------------------------
// K3: cost volume via bf16 MFMA -> padded bf16 cvp [4][70][70][320] at (+3,+3).
// 4-output-row strips, 512 threads (8 waves): staged x2 traffic 156 -> 82 MB,
// per-XCD unique x2 slice 16.4 -> 3.9 MB (now fits the 4 MB XCD L2).
// Same MFMA count and same 8 waves/CU as the 2-row version.
__global__ __launch_bounds__(512, 2)
void cv_mfma_kernel(const unsigned short* __restrict__ x1b,
                    const unsigned short* __restrict__ x2b,
                    unsigned short* __restrict__ cvp) {
    __shared__ __align__(16) unsigned short x2s[2][32 * ASTR];
    int i = blockIdx.x;                    // 256
    int xcd = i & 7;
    int j = i >> 3;
    int hp = xcd * 2 + (j & 1);            // 0..15
    int jj = j >> 1;
    int wseg = jj & 3;
    int b = jj >> 2;
    int h0 = hp * 4;
    int w0 = wseg * 16;
    int t = threadIdx.x;
    int wave = t >> 6, lane = t & 63;
    int lrow = lane & 15, quad = lane >> 4;
    int row_w = wave >> 1, ct = wave & 1;  // row 0..3, col-half 0..1
    int h = h0 + row_w;
    int col_l = ct * 16 + lrow;

    const unsigned short* x1p = x1b + ((size_t)b * HW + h * 64 + w0) * C;
    bf16x8 a[8];
#pragma unroll
    for (int kk = 0; kk < 8; ++kk)
        a[kk] = *(const bf16x8*)&x1p[(size_t)lrow * C + kk * 32 + quad * 8];

    const unsigned short* x2base = x2b + (size_t)b * PH * PW * C;

    {
        const unsigned short* rowp = x2base + ((size_t)h0 * PW + w0) * C;
#pragma unroll
        for (int s = 0; s < 2; ++s) {
            int v = t + s * 512;
            int col = v >> 5, ch8 = v & 31;
            *(us8*)&x2s[0][col * ASTR + ch8 * 8] = *(const us8*)&rowp[(size_t)col * C + ch8 * 8];
        }
    }
    __syncthreads();

    for (int rr = 0; rr < 20; ++rr) {
        us8 pr[2];
        bool dop = (rr + 1 < 20);
        if (dop) {
            const unsigned short* rowp = x2base + ((size_t)(h0 + rr + 1) * PW + w0) * C;
#pragma unroll
            for (int s = 0; s < 2; ++s) {
                int v = t + s * 512;
                int col = v >> 5, ch8 = v & 31;
                pr[s] = *(const us8*)&rowp[(size_t)col * C + ch8 * 8];
            }
        }

        int dj = rr - row_w;
        if ((unsigned)dj <= 16u) {
            const unsigned short* xs = x2s[rr & 1];
            f32x4 acc = {0.f, 0.f, 0.f, 0.f};
#pragma unroll
            for (int kk = 0; kk < 8; ++kk) {
                bf16x8 bb = *(const bf16x8*)&xs[col_l * ASTR + kk * 32 + quad * 8];
                acc = __builtin_amdgcn_mfma_f32_16x16x32_bf16(a[kk], bb, acc, 0, 0, 0);
            }
#pragma unroll
            for (int r = 0; r < 4; ++r) {
                int px_l = quad * 4 + r;
                int di = col_l - px_l;
                if ((unsigned)di <= 16u) {
                    float v = acc[r] * (1.0f / 256.0f);
                    v = (v > 0.f) ? v : 0.1f * v;
                    __hip_bfloat16 hb = __float2bfloat16(v);
                    cvp[(((size_t)b * CVP + h + 3) * CVP + (w0 + px_l + 3)) * CVC + dj * MO + di] =
                        *(unsigned short*)&hb;
                }
            }
        }

        if (dop) {
            unsigned short* dst = x2s[(rr + 1) & 1];
#pragma unroll
            for (int s = 0; s < 2; ++s) {
                int v = t + s * 512;
                int col = v >> 5, ch8 = v & 31;
                *(us8*)&dst[col * ASTR + ch8 * 8] = pr[s];
            }
            __syncthreads();
        }
    }
}

// ---------------------------------------------------------------------------
// K4: depthwise 7x7 attention conv + multiply. actS kept in bf16 (25 KB) so
// LDS = 37.6 KB -> 4 blocks/CU (was 2). Values identical (bf16->f32 exact).
__global__ __launch_bounds__(256, 4)
void dw_att_tiled(const unsigned short* __restrict__ cvp,
                  const float* __restrict__ wdwp,
                  const float* __restrict__ att_b, unsigned short* __restrict__ av_pad) {
    __shared__ __align__(16) unsigned short actS[14 * 14 * 64];   // 25 KB bf16
    __shared__ float wdwS[49 * 64];                                // 12.5 KB
    int i = blockIdx.x;                    // 1280
    int ty = i & 7;
    int j = i >> 3;
    int cc = j % 5;
    int rest = j / 5;
    int tx = rest & 7, b = rest >> 3;
    int x0 = tx * 8, y0 = ty * 8;
    int c0 = cc * 64;
    int t = threadIdx.x;

    const unsigned short* cvb = cvp + (((size_t)b * CVP + y0) * CVP + x0) * CVC + c0;
    for (int v = t; v < 14 * 14 * 8; v += 256) {
        int rc = v >> 3, c8v = v & 7;
        int yy = rc / 14, xx = rc - yy * 14;
        *(us8*)&actS[rc * 64 + c8v * 8] =
            *(const us8*)&cvb[((size_t)yy * CVP + xx) * CVC + c8v * 8];
    }
    for (int v = t; v < 49 * 64; v += 256) {
        int tap = v >> 6, ch = v & 63;
        wdwS[v] = wdwp[tap * CVC + c0 + ch];
    }
    __syncthreads();

    int ch_l = t & 63, pgrp = t >> 6;
    int ch = c0 + ch_l;
    float bv = (ch < NCH) ? att_b[ch] : 0.f;
    float acc[16];
#pragma unroll
    for (int ii = 0; ii < 16; ++ii) acc[ii] = bv;

    for (int dy = 0; dy < 7; ++dy) {
        float wreg[7];
#pragma unroll
        for (int dx = 0; dx < 7; ++dx)
            wreg[dx] = wdwS[(dy * 7 + dx) * 64 + ch_l];
#pragma unroll
        for (int py2 = 0; py2 < 2; ++py2) {
            int row = pgrp * 2 + py2 + dy;
            float rowv[14];
#pragma unroll
            for (int xx = 0; xx < 14; ++xx) {
                __bf16 bvv = *(const __bf16*)&actS[(row * 14 + xx) * 64 + ch_l];
                rowv[xx] = (float)bvv;
            }
#pragma unroll
            for (int dx = 0; dx < 7; ++dx)
#pragma unroll
                for (int px = 0; px < 8; ++px)
                    acc[py2 * 8 + px] += rowv[px + dx] * wreg[dx];
        }
    }

    if (ch < NCH) {
#pragma unroll
        for (int ii = 0; ii < 16; ++ii) {
            int py = pgrp * 2 + (ii >> 3), px = ii & 7;
            __bf16 cb = *(const __bf16*)&actS[((py + 3) * 14 + (px + 3)) * 64 + ch_l];
            float c0v = (float)cb;
            __hip_bfloat16 hb = __float2bfloat16(c0v * acc[ii]);
            av_pad[(((size_t)b * 66 + y0 + py + 1) * 66 + (x0 + px + 1)) * ICP + ch] =
                *(unsigned short*)&hb;
        }
    }
}

// ---------------------------------------------------------------------------
// K5: conv3x3 289->144 + ReLU via bf16 MFMA, software-pipelined, XCD-banded.
__global__ void agg1_mfma_kernel(const unsigned short* __restrict__ av_pad,
                                 const unsigned short* __restrict__ wb1,
                                 const float* __restrict__ bias,
                                 unsigned short* __restrict__ h1p) {
    __shared__ __align__(16) unsigned short aS2[2][66 * CH64];
    __shared__ __align__(16) unsigned short bS[2][C1 * CH64];
    int i = blockIdx.x;                    // 256
    int xcd = i & 7;
    int j = i >> 3;
    int h = xcd * 8 + (j & 7);
    int b = j >> 3;
    int t = threadIdx.x;
    int wave = t >> 6, lane = t & 63;
    int lrow = lane & 15, quad = lane >> 4;
    int ot0 = (wave == 0) ? 0 : (wave * 2 + 1);
    int nt  = (wave == 0) ? 3 : 2;

    f32x4 acc[4][3];
#pragma unroll
    for (int m = 0; m < 4; ++m)
#pragma unroll
        for (int ii = 0; ii < 3; ++ii) acc[m][ii] = (f32x4){0.f, 0.f, 0.f, 0.f};

    const unsigned short* avb = av_pad + (((size_t)b * 66 + h) * 66) * ICP;

    {
        const unsigned short* arow = avb;
#pragma unroll
        for (int s = 0; s < 2; ++s) {
            int v = t + s * 256;
            *(us8*)&aS2[0][(v >> 3) * CH64 + (v & 7) * 8] =
                *(const us8*)&arow[(size_t)(v >> 3) * ICP + (v & 7) * 8];
        }
        if (t < 16) {
            int v = t + 512;
            *(us8*)&aS2[0][(v >> 3) * CH64 + (v & 7) * 8] =
                *(const us8*)&arow[(size_t)(v >> 3) * ICP + (v & 7) * 8];
        }
#pragma unroll
        for (int s = 0; s < 4; ++s) {
            int v = t + s * 256;
            *(us8*)&bS[0][(v >> 3) * CH64 + (v & 7) * 8] =
                *(const us8*)&wb1[(size_t)(v >> 3) * ICP + (v & 7) * 8];
        }
        if (t < 128) {
            int v = t + 1024;
            *(us8*)&bS[0][(v >> 3) * CH64 + (v & 7) * 8] =
                *(const us8*)&wb1[(size_t)(v >> 3) * ICP + (v & 7) * 8];
        }
    }
    __syncthreads();

    for (int k = 0; k < 45; ++k) {
        int rr = k % 15;
        int dx = rr % 3;
        int abuf = (k / 3) & 1, bbuf = k & 1;

        us8 br[5], ar[3];
        int kn = k + 1;
        bool do_b = (kn < 45);
        bool do_a = do_b && (kn % 3 == 0);
        int dyn = kn / 15, rn = kn % 15;
        int ccin = rn / 3, dxn = rn % 3;
        if (do_b) {
            const unsigned short* wt = wb1 + ((size_t)(dyn * 3 + dxn) * C1) * ICP + ccin * 64;
#pragma unroll
            for (int s = 0; s < 4; ++s) {
                int v = t + s * 256;
                br[s] = *(const us8*)&wt[(size_t)(v >> 3) * ICP + (v & 7) * 8];
            }
            if (t < 128) {
                int v = t + 1024;
                br[4] = *(const us8*)&wt[(size_t)(v >> 3) * ICP + (v & 7) * 8];
            }
        }
        if (do_a) {
            const unsigned short* arow = avb + (size_t)dyn * 66 * ICP + ccin * 64;
#pragma unroll
            for (int s = 0; s < 2; ++s) {
                int v = t + s * 256;
                ar[s] = *(const us8*)&arow[(size_t)(v >> 3) * ICP + (v & 7) * 8];
            }
            if (t < 16) {
                int v = t + 512;
                ar[2] = *(const us8*)&arow[(size_t)(v >> 3) * ICP + (v & 7) * 8];
            }
        }

        const unsigned short* aP = aS2[abuf];
        const unsigned short* bP = bS[bbuf];
#pragma unroll
        for (int cc2 = 0; cc2 < 2; ++cc2) {
            bf16x8 bfr[3];
#pragma unroll
            for (int ii = 0; ii < 3; ++ii)
                if (ii < nt)
                    bfr[ii] = *(const bf16x8*)&bP[((ot0 + ii) * 16 + lrow) * CH64 + cc2 * 32 + quad * 8];
#pragma unroll
            for (int m = 0; m < 4; ++m) {
                bf16x8 af = *(const bf16x8*)&aP[(m * 16 + lrow + dx) * CH64 + cc2 * 32 + quad * 8];
#pragma unroll
                for (int ii = 0; ii < 3; ++ii)
                    if (ii < nt)
                        acc[m][ii] = __builtin_amdgcn_mfma_f32_16x16x32_bf16(af, bfr[ii], acc[m][ii], 0, 0, 0);
            }
        }

        if (do_b) {
            unsigned short* dst = bS[bbuf ^ 1];
#pragma unroll
            for (int s = 0; s < 4; ++s) {
                int v = t + s * 256;
                *(us8*)&dst[(v >> 3) * CH64 + (v & 7) * 8] = br[s];
            }
            if (t < 128) {
                int v = t + 1024;
                *(us8*)&dst[(v >> 3) * CH64 + (v & 7) * 8] = br[4];
            }
        }
        if (do_a) {
            unsigned short* dst = aS2[abuf ^ 1];
#pragma unroll
            for (int s = 0; s < 2; ++s) {
                int v = t + s * 256;
                *(us8*)&dst[(v >> 3) * CH64 + (v & 7) * 8] = ar[s];
            }
            if (t < 16) {
                int v = t + 512;
                *(us8*)&dst[(v >> 3) * CH64 + (v & 7) * 8] = ar[2];
            }
        }
        if (do_b) __syncthreads();
    }

    size_t rowbase = ((size_t)b * 66 + h + 1) * 66;
#pragma unroll
    for (int m = 0; m < 4; ++m)
#pragma unroll
        for (int ii = 0; ii < 3; ++ii)
            if (ii < nt) {
                int oc = (ot0 + ii) * 16 + lrow;
                float bv = bias[oc];
#pragma unroll
                for (int r = 0; r < 4; ++r) {
                    int w = m * 16 + quad * 4 + r;
                    float val = fmaxf(acc[m][ii][r] + bv, 0.f);
                    __hip_bfloat16 hb = __float2bfloat16(val);
                    h1p[(rowbase + (w + 1)) * IC3 + oc] = *(unsigned short*)&hb;
                }
            }
}

// ---------------------------------------------------------------------------
// K6: conv3x3 144->49 + ReLU via bf16 MFMA, software-pipelined. XCD-banded.
__global__ void agg2_mfma_kernel(const unsigned short* __restrict__ h1p,
                                 const unsigned short* __restrict__ wb2,
                                 const float* __restrict__ bias, float* __restrict__ out) {
    __shared__ __align__(16) unsigned short aS2[2][66 * CH64];
    __shared__ __align__(16) unsigned short bS2[2][64 * CH64];
    int i = blockIdx.x;                    // 256
    int xcd = i & 7;
    int j = i >> 3;
    int h = xcd * 8 + (j & 7);
    int b = j >> 3;
    int t = threadIdx.x;
    int wave = t >> 6, lane = t & 63;
    int lrow = lane & 15, quad = lane >> 4;
    int pt = wave;

    f32x4 acc[4];
#pragma unroll
    for (int ot = 0; ot < 4; ++ot) acc[ot] = (f32x4){0.f, 0.f, 0.f, 0.f};

    const unsigned short* h1b = h1p + (((size_t)b * 66 + h) * 66) * IC3;

    {
#pragma unroll
        for (int s = 0; s < 2; ++s) {
            int v = t + s * 256;
            *(us8*)&aS2[0][(v >> 3) * CH64 + (v & 7) * 8] =
                *(const us8*)&h1b[(size_t)(v >> 3) * IC3 + (v & 7) * 8];
        }
        if (t < 16) {
            int v = t + 512;
            *(us8*)&aS2[0][(v >> 3) * CH64 + (v & 7) * 8] =
                *(const us8*)&h1b[(size_t)(v >> 3) * IC3 + (v & 7) * 8];
        }
#pragma unroll
        for (int s = 0; s < 2; ++s) {
            int v = t + s * 256;
            *(us8*)&bS2[0][(v >> 3) * CH64 + (v & 7) * 8] =
                *(const us8*)&wb2[(size_t)(v >> 3) * IC3 + (v & 7) * 8];
        }
    }
    __syncthreads();

    for (int k = 0; k < 27; ++k) {
        int rem = k % 9;
        int dx = rem % 3;
        int abuf = (k / 3) & 1, bbuf = k & 1;

        us8 br[2], ar[3];
        int kn = k + 1;
        bool do_b = (kn < 27);
        bool do_a = do_b && (kn % 3 == 0);
        int dyn = kn / 9, rn = kn % 9;
        int ccn = rn / 3, dxn = rn % 3;
        if (do_b) {
            const unsigned short* wt = wb2 + ((size_t)(dyn * 3 + dxn) * 64) * IC3 + ccn * 64;
#pragma unroll
            for (int s = 0; s < 2; ++s) {
                int v = t + s * 256;
                br[s] = *(const us8*)&wt[(size_t)(v >> 3) * IC3 + (v & 7) * 8];
            }
        }
        if (do_a) {
            const unsigned short* arow = h1b + (size_t)dyn * 66 * IC3 + ccn * 64;
#pragma unroll
            for (int s = 0; s < 2; ++s) {
                int v = t + s * 256;
                ar[s] = *(const us8*)&arow[(size_t)(v >> 3) * IC3 + (v & 7) * 8];
            }
            if (t < 16) {
                int v = t + 512;
                ar[2] = *(const us8*)&arow[(size_t)(v >> 3) * IC3 + (v & 7) * 8];
            }
        }

        const unsigned short* aP = aS2[abuf];
        const unsigned short* bP = bS2[bbuf];
#pragma unroll
        for (int cc2 = 0; cc2 < 2; ++cc2) {
            bf16x8 af = *(const bf16x8*)&aP[(pt * 16 + lrow + dx) * CH64 + cc2 * 32 + quad * 8];
#pragma unroll
            for (int ot = 0; ot < 4; ++ot) {
                bf16x8 bfr = *(const bf16x8*)&bP[(ot * 16 + lrow) * CH64 + cc2 * 32 + quad * 8];
                acc[ot] = __builtin_amdgcn_mfma_f32_16x16x32_bf16(af, bfr, acc[ot], 0, 0, 0);
            }
        }

        if (do_b) {
            unsigned short* dst = bS2[bbuf ^ 1];
#pragma unroll
            for (int s = 0; s < 2; ++s) {
                int v = t + s * 256;
                *(us8*)&dst[(v >> 3) * CH64 + (v & 7) * 8] = br[s];
            }
        }
        if (do_a) {
            unsigned short* dst = aS2[abuf ^ 1];
#pragma unroll
            for (int s = 0; s < 2; ++s) {
                int v = t + s * 256;
                *(us8*)&dst[(v >> 3) * CH64 + (v & 7) * 8] = ar[s];
            }
            if (t < 16) {
                int v = t + 512;
                *(us8*)&dst[(v >> 3) * CH64 + (v & 7) * 8] = ar[2];
            }
        }
        if (do_b) __syncthreads();
    }

#pragma unroll
    for (int ot = 0; ot < 4; ++ot) {
        int o = ot * 16 + lrow;
        if (o < C2) {
            float bv = bias[o];
#pragma unroll
            for (int r = 0; r < 4; ++r) {
                int w = pt * 16 + quad * 4 + r;
                out[((size_t)b * C2 + o) * HW + h * 64 + w] = fmaxf(acc[ot][r] + bv, 0.f);
            }
        }
    }
}

// ---------------------------------------------------------------------------
extern "C" void kernel_launch(void* const* d_in, const int* in_sizes, int n_in,
                              void* d_out, int out_size, void* d_ws, size_t ws_size,
                              hipStream_t stream) {
    const float* f1    = (const float*)d_in[0];
    const float* f2    = (const float*)d_in[1];
    const float* att_w = (const float*)d_in[2];
    const float* att_b = (const float*)d_in[3];
    const float* w1    = (const float*)d_in[4];
    const float* b1    = (const float*)d_in[5];
    const float* w2    = (const float*)d_in[6];
    const float* b2    = (const float*)d_in[7];
    float* out = (float*)d_out;

    char* wsb = (char*)d_ws;
    size_t off = 0;
    float* wdwp = (float*)(wsb + off); off += (size_t)49 * CVC * 4;
    off = (off + 15) & ~(size_t)15;
    unsigned short* x1bf = (unsigned short*)(wsb + off); off += (size_t)NPIX * C * 2;
    unsigned short* x2bf = (unsigned short*)(wsb + off); off += (size_t)BS * PH * PW * C * 2;
    unsigned short* cvp  = (unsigned short*)(wsb + off); off += (size_t)BS * CVP * CVP * CVC * 2;
    unsigned short* avp  = (unsigned short*)(wsb + off); off += (size_t)BS * 66 * 66 * ICP * 2;
    unsigned short* wb1  = (unsigned short*)(wsb + off); off += (size_t)9 * C1 * ICP * 2;
    unsigned short* h1p  = (unsigned short*)(wsb + off); off += (size_t)BS * 66 * 66 * IC3 * 2;
    unsigned short* wb2  = (unsigned short*)(wsb + off); off += (size_t)9 * 64 * IC3 * 2;
    if (ws_size < off) return;

    setup_kernel<<<9150, 256, 0, stream>>>(x2bf, cvp, avp, h1p, w1, wb1, w2, wb2,
                                           att_w, wdwp, f1, x1bf, f2);
    cv_mfma_kernel<<<256, 512, 0, stream>>>(x1bf, x2bf, cvp);
    dw_att_tiled<<<1280, 256, 0, stream>>>(cvp, wdwp, att_b, avp);
    agg1_mfma_kernel<<<256, 256, 0, stream>>>(avp, wb1, b1, h1p);
    agg2_mfma_kernel<<<256, 256, 0, stream>>>(h1p, wb2, b2, out);
}